// Round 3
// baseline (2232.748 us; speedup 1.0000x reference)
//
#include <hip/hip_runtime.h>
#include <math.h>

typedef _Float16 f16;
typedef _Float16 f16x8 __attribute__((ext_vector_type(8)));
typedef _Float16 f16x4 __attribute__((ext_vector_type(4)));
typedef float    f32x4 __attribute__((ext_vector_type(4)));

#define NB 16
#define NP 2048
#define NH 2048
#define ND 1024
#define MT 16          // premise rows per block (R3: halved -> 3 blocks/CU)
#define NT 64          // hypothesis cols per iteration
#define SCALE 0.03125f // 1/sqrt(1024), exact power of 2 -> folded into Q f16

// ---------------------------------------------------------------------------
// Prep: hypothesis fp32 -> f16, two layouts:
//   KVh[b][h][d]  (QK^T B-operand: contraction along d, rows contiguous in d)
//   KVt[b][d][h]  (PV   B-operand: contraction along h, rows contiguous in h)
// R3: skip fully-masked h-tiles (never read by main); 16B stores.
// ---------------------------------------------------------------------------
__global__ __launch_bounds__(256)
void prep(const float* __restrict__ KV, const float* __restrict__ HM,
          f16* __restrict__ KVh, f16* __restrict__ KVt)
{
  __shared__ f16 tile[64][68];           // +4 f16 pad
  const int bb = blockIdx.z;
  const int h0 = blockIdx.y << 6;
  const int d0 = blockIdx.x << 6;
  if (HM[(size_t)bb * NH + h0] == 0.0f) return;   // tile never read downstream
  const int tid = threadIdx.x;
  const int r0 = tid >> 3;               // 0..31
  const int c0 = (tid & 7) << 3;         // 0,8,..,56
#pragma unroll
  for (int i = 0; i < 2; ++i) {
    const int r = r0 + (i << 5);
    f32x4 x = *(const f32x4*)(KV + ((size_t)(bb * NH + h0 + r)) * ND + d0 + c0);
    f32x4 y = *(const f32x4*)(KV + ((size_t)(bb * NH + h0 + r)) * ND + d0 + c0 + 4);
    f16x8 hv;
    hv[0] = (f16)x[0]; hv[1] = (f16)x[1]; hv[2] = (f16)x[2]; hv[3] = (f16)x[3];
    hv[4] = (f16)y[0]; hv[5] = (f16)y[1]; hv[6] = (f16)y[2]; hv[7] = (f16)y[3];
    *(f16x8*)(KVh + ((size_t)(bb * NH + h0 + r)) * ND + d0 + c0) = hv;
    *(f16x8*)&tile[r][c0] = hv;
  }
  __syncthreads();
#pragma unroll
  for (int i = 0; i < 2; ++i) {
    const int dr = r0 + (i << 5);        // d-row within tile
    f16x8 hv;
#pragma unroll
    for (int j = 0; j < 8; ++j) hv[j] = tile[c0 + j][dr];
    *(f16x8*)(KVt + ((size_t)(bb * ND + d0 + dr)) * NH + h0 + c0) = hv;
  }
}

// ---------------------------------------------------------------------------
// Main: flash-style uni-attention. MFMA 16x16x32 f16 layouts (HW-verified):
//   A: m = lane&15, k = (lane>>4)*8 + j ;  B: n = lane&15, k = (lane>>4)*8 + j
//   C/D: col = lane&15, row = (lane>>4)*4 + reg
// R3: MT=16, 4 waves; wave w owns S col-tile w (no K redundancy) and
//     O d-slice [w*256,+256) (Oacc 64 AGPR). Softmax state (m,l,alpha) kept
//     per-lane and computed redundantly by every wave -> 2 barriers/tile,
//     no divergent designated-wave sections. Simple loop bodies (no manual
//     dbuf, no setprio - R2 post-mortem). XCD swizzle kept.
// ---------------------------------------------------------------------------
__global__ __launch_bounds__(256, 3)
void uniattn(const float* __restrict__ Q,   const float* __restrict__ PM,
             const f16*   __restrict__ KVh, const f16*   __restrict__ KVt,
             const float* __restrict__ HM,  float* __restrict__ OUT)
{
  // XCD-aware swizzle: 2048 blocks % 8 XCDs == 0 -> bijective.
  // Each XCD gets 256 consecutive logical blocks = 2 complete batches.
  const int orig = blockIdx.x;
  const int bid  = ((orig & 7) << 8) + (orig >> 3);
  const int b    = bid >> 7;           // 128 p-tiles per batch
  const int p0   = (bid & 127) * MT;
  const int tid  = threadIdx.x;
  const int w    = tid >> 6;           // wave 0..3 = S col-tile = O d-slice
  const int lane = tid & 63;
  const int qd   = lane >> 4;          // quad 0..3
  const int c16  = lane & 15;

  // ---- premise-mask block skip (mask is monotone: arange < len) ----
  if (PM[(size_t)b * NP + p0] == 0.0f) {
    float* ob = OUT + ((size_t)b * NP + p0) * ND;
    const f32x4 z = {0.f, 0.f, 0.f, 0.f};
#pragma unroll
    for (int i = 0; i < 16; ++i)
      *(f32x4*)(ob + (size_t)((i << 8) + tid) * 4) = z;
    return;
  }

  __shared__ f16 Qs[16 * 1024];        // 32KB: Q tile, f16, scaled, swizzled
  __shared__ float pm_s[4][16];        // per-wave partial row max
  __shared__ float pl_s[4][16];        // per-wave partial row sum
  __shared__ int   nt_s;               // valid h-tile count
  __shared__ __align__(16) f16 Pt[16][72];  // P~ tile, +8 f16 pad

  const float* hm = HM + (size_t)b * NH;

  // ---- stage Q tile into LDS (fp32 -> f16 * SCALE), 16B-chunk XOR swizzle ----
  {
    const float* Qb = Q + ((size_t)b * NP + p0) * ND;
#pragma unroll
    for (int i = 0; i < 8; ++i) {
      const int g = (i << 8) + tid;    // chunk id 0..2047 (8 f16 each)
      const int r = g >> 7;            // row 0..15
      const int c = g & 127;           // chunk-in-row
      f32x4 x = *(const f32x4*)(Qb + (size_t)r * ND + (c << 3));
      f32x4 y = *(const f32x4*)(Qb + (size_t)r * ND + (c << 3) + 4);
      f16x8 hv;
      hv[0] = (f16)(x[0] * SCALE); hv[1] = (f16)(x[1] * SCALE);
      hv[2] = (f16)(x[2] * SCALE); hv[3] = (f16)(x[3] * SCALE);
      hv[4] = (f16)(y[0] * SCALE); hv[5] = (f16)(y[1] * SCALE);
      hv[6] = (f16)(y[2] * SCALE); hv[7] = (f16)(y[3] * SCALE);
      *(f16x8*)&Qs[(r << 10) + ((c ^ (r & 7)) << 3)] = hv;
    }
  }
  // ---- valid h-tile count via ballot (hm monotone, len >= NH/2) ----
  if (w == 0) {
    const int idx = (lane < 32) ? (lane << 6) : 0;   // lanes>=32 read hm[0]==1
    unsigned long long bal = __ballot(hm[idx] != 0.0f);
    if (lane == 0) nt_s = __popcll(bal) - 32;
  }
  __syncthreads();
  const int ntiles = nt_s;

  // Per-lane softmax state, rows qd*4+rg (identical across c16 and waves).
  float mrun[4] = {-1e30f, -1e30f, -1e30f, -1e30f};
  float lrun[4] = {0.f, 0.f, 0.f, 0.f};

  // O accumulator: wave w owns d-cols [w*256, w*256+256): 16 col-tiles x 4 rows
  f32x4 Oacc[16];
#pragma unroll
  for (int t = 0; t < 16; ++t) Oacc[t] = (f32x4){0.f, 0.f, 0.f, 0.f};

  const f16* Kb = KVh + (size_t)b * NH * ND;
  const f16* Vt = KVt + (size_t)b * ND * NH;
  const int dbase = w << 8;
  const int sx = c16 & 7;              // Qs swizzle key (A-frag row = c16)
  const f16* krA = Kb + (size_t)((w << 4) + c16) * ND + (qd << 3);
  const f16* vrow = Vt + (size_t)(dbase + c16) * NH + (qd << 3);

#pragma unroll 1
  for (int it = 0; it < ntiles; ++it) {
    const int h0 = it << 6;
    // ---------- Phase A: S(16x16) = Q Ktile_w^T, full unroll, plain loads ----
    const f16* kr = krA + (size_t)h0 * ND;
    const float km = hm[h0 + (w << 4) + c16];
    f32x4 S = {0.f, 0.f, 0.f, 0.f};
#pragma unroll
    for (int kc = 0; kc < 32; ++kc) {
      f16x8 af = *(const f16x8*)&Qs[(c16 << 10) + ((((kc << 2) + qd) ^ sx) << 3)];
      f16x8 kb = *(const f16x8*)(kr + (kc << 5));
      S = __builtin_amdgcn_mfma_f32_16x16x32_f16(af, kb, S, 0, 0, 0);
    }

    // ---------- Online softmax (per-lane state, redundant across waves) ----
    float sm[4], mx[4];
#pragma unroll
    for (int rg = 0; rg < 4; ++rg) {
      sm[rg] = (km != 0.f) ? S[rg] : -1e30f;
      mx[rg] = sm[rg];
    }
#pragma unroll
    for (int sh = 1; sh < 16; sh <<= 1)
#pragma unroll
      for (int rg = 0; rg < 4; ++rg)
        mx[rg] = fmaxf(mx[rg], __shfl_xor(mx[rg], sh));
    if (c16 == 0) {
#pragma unroll
      for (int rg = 0; rg < 4; ++rg) pm_s[w][qd * 4 + rg] = mx[rg];
    }
    __syncthreads();                   // barrier 1: pm_s ready; Pt safe to write

    float al[4], ls[4];
#pragma unroll
    for (int rg = 0; rg < 4; ++rg) {
      const int row = qd * 4 + rg;
      const float mt = fmaxf(fmaxf(pm_s[0][row], pm_s[1][row]),
                             fmaxf(pm_s[2][row], pm_s[3][row]));
      const float mn = fmaxf(mrun[rg], mt);
      al[rg]   = __expf(mrun[rg] - mn);
      mrun[rg] = mn;
      const float pv = km * __expf(sm[rg] - mn);
      Pt[row][(w << 4) + c16] = (f16)pv;
      ls[rg] = pv;
    }
#pragma unroll
    for (int sh = 1; sh < 16; sh <<= 1)
#pragma unroll
      for (int rg = 0; rg < 4; ++rg)
        ls[rg] += __shfl_xor(ls[rg], sh);
    if (c16 == 0) {
#pragma unroll
      for (int rg = 0; rg < 4; ++rg) pl_s[w][qd * 4 + rg] = ls[rg];
    }
    __syncthreads();                   // barrier 2: Pt + pl_s complete

#pragma unroll
    for (int rg = 0; rg < 4; ++rg) {
      const int row = qd * 4 + rg;
      lrun[rg] = lrun[rg] * al[rg] +
                 (pl_s[0][row] + pl_s[1][row]) + (pl_s[2][row] + pl_s[3][row]);
    }

    // ---------- Phase C: O = O*alpha + P~ V ; wave owns d-slice [w*256,+256) --
#pragma unroll
    for (int t = 0; t < 16; ++t)
#pragma unroll
      for (int rg = 0; rg < 4; ++rg) Oacc[t][rg] *= al[rg];
    const f16* vc = vrow + h0;
#pragma unroll
    for (int kcc = 0; kcc < 2; ++kcc) {
      f16x8 pa = *(const f16x8*)&Pt[c16][kcc * 32 + (qd << 3)];
#pragma unroll
      for (int t = 0; t < 16; ++t) {   // FULL unroll: Oacc stays in registers
        f16x8 vb = *(const f16x8*)(vc + (kcc << 5) + (size_t)t * (16 * NH));
        Oacc[t] = __builtin_amdgcn_mfma_f32_16x16x32_f16(pa, vb, Oacc[t], 0, 0, 0);
      }
    }
    // no barrier here: next iteration's Pt/pm writes occur only after
    // barrier 1', which every wave reaches after finishing this phase C.
  }

  // ---------- Epilogue: out = O / l * premise_mask (per-lane rec) ----------
#pragma unroll
  for (int rg = 0; rg < 4; ++rg) {
    const float rv = PM[(size_t)b * NP + p0 + qd * 4 + rg] / (lrun[rg] + 1e-13f);
#pragma unroll
    for (int t = 0; t < 16; ++t) {
      float* op = OUT + ((size_t)b * NP + p0 + qd * 4 + rg) * ND
                      + dbase + t * 16 + c16;
      *op = Oacc[t][rg] * rv;
    }
  }
}

extern "C" void kernel_launch(void* const* d_in, const int* in_sizes, int n_in,
                              void* d_out, int out_size, void* d_ws, size_t ws_size,
                              hipStream_t stream) {
  const float* Q  = (const float*)d_in[0];  // premise_batch   [16][2048][1024]
  const float* PM = (const float*)d_in[1];  // premise_mask    [16][2048]
  const float* KV = (const float*)d_in[2];  // hypothesis_batch[16][2048][1024]
  const float* HM = (const float*)d_in[3];  // hypothesis_mask [16][2048]
  float* OUT = (float*)d_out;               // [16][2048][1024] fp32

  // workspace: KVh (64MB) + KVt (64MB) = 128MB f16 copies of hypothesis
  f16* KVh = (f16*)d_ws;
  f16* KVt = KVh + (size_t)NB * NH * ND;
  (void)ws_size; (void)in_sizes; (void)n_in; (void)out_size;

  dim3 pgrid(ND / 64, NH / 64, NB);         // 8192 blocks (masked tiles exit)
  hipLaunchKernelGGL(prep, pgrid, dim3(256), 0, stream, KV, HM, KVh, KVt);

  dim3 grid(NB * (NP / MT));                // 2048 blocks
  hipLaunchKernelGGL(uniattn, grid, dim3(256), 0, stream, Q, PM, KVh, KVt, HM, OUT);
}